// Round 3
// baseline (789.414 us; speedup 1.0000x reference)
//
#include <hip/hip_runtime.h>
#include <cstddef>

#define D 128
#define EPSV 1e-9f
#define NB 8

__device__ __forceinline__ float wred64(float v) {
    #pragma unroll
    for (int off = 32; off > 0; off >>= 1) v += __shfl_xor(v, off, 64);
    return v;
}

// ===========================================================================
// CSR build: histogram -> 3-stage exclusive scan -> scatter (col,val) by row
// ===========================================================================
__global__ __launch_bounds__(256) void hist_kernel(
    const int* __restrict__ erow, int* __restrict__ counts, int nE)
{
    int i = blockIdx.x * 256 + threadIdx.x;
    if (i < nE) atomicAdd(&counts[erow[i]], 1);
}

__global__ __launch_bounds__(1024) void scan1_kernel(
    const int* __restrict__ in, int* __restrict__ out,
    int* __restrict__ sums, int n)
{
    __shared__ int tmp[1024];
    const int t = threadIdx.x;
    const int gid = blockIdx.x * 1024 + t;
    const int v = (gid < n) ? in[gid] : 0;
    tmp[t] = v;
    __syncthreads();
    #pragma unroll
    for (int d = 1; d < 1024; d <<= 1) {
        int u = (t >= d) ? tmp[t - d] : 0;
        __syncthreads();
        tmp[t] += u;
        __syncthreads();
    }
    if (gid < n) out[gid] = tmp[t] - v;
    if (t == 1023) sums[blockIdx.x] = tmp[t];
}

__global__ __launch_bounds__(1024) void scan2_kernel(int* __restrict__ sums, int nb)
{
    __shared__ int tmp[1024];
    const int t = threadIdx.x;
    const int v = (t < nb) ? sums[t] : 0;
    tmp[t] = v;
    __syncthreads();
    #pragma unroll
    for (int d = 1; d < 1024; d <<= 1) {
        int u = (t >= d) ? tmp[t - d] : 0;
        __syncthreads();
        tmp[t] += u;
        __syncthreads();
    }
    if (t < nb) sums[t] = tmp[t] - v;
}

__global__ __launch_bounds__(1024) void scan3_kernel(
    int* __restrict__ out, const int* __restrict__ sums, int n)
{
    int gid = blockIdx.x * 1024 + threadIdx.x;
    if (gid < n) out[gid] += sums[blockIdx.x];
}

__global__ __launch_bounds__(256) void scatter_kernel(
    const int* __restrict__ erow, const int* __restrict__ ecol,
    const float* __restrict__ eval_, const int* __restrict__ rowptr,
    int* __restrict__ fill, int2* __restrict__ esort, int nE)
{
    int i = blockIdx.x * 256 + threadIdx.x;
    if (i < nE) {
        const int r = erow[i];
        const int pos = rowptr[r] + atomicAdd(&fill[r], 1);
        esort[pos] = make_int2(ecol[i], __float_as_int(eval_[i]));
    }
}

// ===========================================================================
// Pull SpMM: one wave per node; unroll-4 edge walk, 2 accumulator chains.
// ===========================================================================
__global__ __launch_bounds__(256) void spmm_pull_kernel(
    const float* __restrict__ x, const int* __restrict__ rowptr,
    const int2* __restrict__ es, float* __restrict__ feat, int nN)
{
    const int lane = threadIdx.x & 63;
    const int node = __builtin_amdgcn_readfirstlane(
        (int)((blockIdx.x * 256 + threadIdx.x) >> 6));
    if (node >= nN) return;
    const int s = rowptr[node];
    const int e = rowptr[node + 1];
    float2 acc = make_float2(0.f, 0.f);
    float2 acc2 = make_float2(0.f, 0.f);
    int j = s;
    for (; j + 3 < e; j += 4) {
        const int2 e0 = es[j];
        const int2 e1 = es[j + 1];
        const int2 e2 = es[j + 2];
        const int2 e3 = es[j + 3];
        const float2 x0 = ((const float2*)(x + (size_t)e0.x * D))[lane];
        const float2 x1 = ((const float2*)(x + (size_t)e1.x * D))[lane];
        const float2 x2 = ((const float2*)(x + (size_t)e2.x * D))[lane];
        const float2 x3 = ((const float2*)(x + (size_t)e3.x * D))[lane];
        const float v0 = __int_as_float(e0.y), v1 = __int_as_float(e1.y);
        const float v2 = __int_as_float(e2.y), v3 = __int_as_float(e3.y);
        acc.x  = fmaf(v0, x0.x, acc.x);  acc.y  = fmaf(v0, x0.y, acc.y);
        acc2.x = fmaf(v1, x1.x, acc2.x); acc2.y = fmaf(v1, x1.y, acc2.y);
        acc.x  = fmaf(v2, x2.x, acc.x);  acc.y  = fmaf(v2, x2.y, acc.y);
        acc2.x = fmaf(v3, x3.x, acc2.x); acc2.y = fmaf(v3, x3.y, acc2.y);
    }
    for (; j < e; ++j) {
        const int2 e0 = es[j];
        const float v0 = __int_as_float(e0.y);
        const float2 x0 = ((const float2*)(x + (size_t)e0.x * D))[lane];
        acc.x = fmaf(v0, x0.x, acc.x);
        acc.y = fmaf(v0, x0.y, acc.y);
    }
    acc.x += acc2.x; acc.y += acc2.y;
    ((float2*)(feat + (size_t)node * D))[lane] = acc;
}

// ===========================================================================
// Fallback (ws too small): push-style SpMM with HW f32 atomics
// ===========================================================================
__global__ __launch_bounds__(256) void spmm_atomic_kernel(
    const float* __restrict__ x, const int* __restrict__ erow,
    const int* __restrict__ ecol, const float* __restrict__ eval_,
    float* __restrict__ feat, int nEdges)
{
    const int lane = threadIdx.x & 63;
    int w = (int)((blockIdx.x * blockDim.x + threadIdx.x) >> 6);
    const int nW = (int)((gridDim.x * blockDim.x) >> 6);
    for (int e = w; e < nEdges; e += nW) {
        const int r = erow[e];
        const int c = ecol[e];
        const float v = eval_[e];
        const float2 xv = ((const float2*)(x + (size_t)c * D))[lane];
        float* fr = feat + (size_t)r * D + 2 * lane;
        unsafeAtomicAdd(fr,     v * xv.x);
        unsafeAtomicAdd(fr + 1, v * xv.y);
    }
}

// ===========================================================================
// GEMM+ELU+norm v2: W in VGPRs (lane owns output column o = (wave&1)*64+lane),
// feat staged in LDS (4KB/iter) and consumed via uniform ds_read_b128
// (broadcast). Pure-FMA inner loop, 4 acc chains. Wave-pair covers 128 outs;
// mean/var via shfl + tiny LDS exchange. In-place on d_out.
// ===========================================================================
__global__ __launch_bounds__(256, 3) void gemm_elu_norm_v2(
    float* io,
    const float* __restrict__ W, const float* __restrict__ bias,
    const float* __restrict__ scale, const float* __restrict__ offset,
    int nNodes)
{
    __shared__ float  lfeat[NB][D];     // 4KB
    __shared__ float2 red[2][4][2];     // pair, node, half

    const int tid  = threadIdx.x;
    const int wave = tid >> 6;
    const int lane = tid & 63;
    const int p = wave >> 1;            // pair 0/1
    const int h = wave & 1;             // which 64-output half
    const int o = h * 64 + lane;        // this lane's output column

    float w[D];
    #pragma unroll
    for (int kb = 0; kb < 32; ++kb) {
        const float4 wv = *(const float4*)&W[(size_t)o * D + kb * 4];
        w[4*kb] = wv.x; w[4*kb+1] = wv.y; w[4*kb+2] = wv.z; w[4*kb+3] = wv.w;
    }
    const float bo = bias[o], sco = scale[o], ofo = offset[o];

    const int r_st = tid >> 5;          // 0..7 (staging row)
    const int q    = tid & 31;          // float4 index within row

    for (int nbase = blockIdx.x * NB; nbase < nNodes; nbase += gridDim.x * NB) {
        // --- stage 8 feat rows (coalesced float4) ---
        {
            const int node = nbase + r_st;
            float4 v = make_float4(0.f, 0.f, 0.f, 0.f);
            if (node < nNodes) v = *(const float4*)&io[(size_t)node * D + q * 4];
            *(float4*)&lfeat[r_st][q * 4] = v;
        }
        __syncthreads();

        // --- compute: each wave does 4 nodes, pure FMA inner loop ---
        float e[4];
        #pragma unroll
        for (int nd = 0; nd < 4; ++nd) {
            const int r = p * 4 + nd;
            float a0 = 0.f, a1 = 0.f, a2 = 0.f, a3 = 0.f;
            #pragma unroll
            for (int kb = 0; kb < 32; ++kb) {
                const float4 f = *(const float4*)&lfeat[r][kb * 4];  // uniform -> broadcast
                a0 = fmaf(f.x, w[4*kb  ], a0);
                a1 = fmaf(f.y, w[4*kb+1], a1);
                a2 = fmaf(f.z, w[4*kb+2], a2);
                a3 = fmaf(f.w, w[4*kb+3], a3);
            }
            float v = (a0 + a1) + (a2 + a3) + bo;
            v = v > 0.f ? v : expm1f(v);
            e[nd] = v;
            const float s  = wred64(v);
            const float sq = wred64(v * v);
            if (lane == 0) red[p][nd][h] = make_float2(s, sq);
        }
        __syncthreads();

        // --- epilogue: combine halves, normalize, store ---
        #pragma unroll
        for (int nd = 0; nd < 4; ++nd) {
            const int node = nbase + p * 4 + nd;
            if (node < nNodes) {
                const float2 r0 = red[p][nd][0];
                const float2 r1 = red[p][nd][1];
                const float s  = r0.x + r1.x;
                const float sq = r0.y + r1.y;
                const float mean = s * (1.0f / D);
                const float var  = sq * (1.0f / D) - mean * mean;
                const float rs   = rsqrtf(var + EPSV);
                io[(size_t)node * D + o] = (e[nd] - mean) * sco * rs + ofo;
            }
        }
        __syncthreads();
    }
}

extern "C" void kernel_launch(void* const* d_in, const int* in_sizes, int n_in,
                              void* d_out, int out_size, void* d_ws, size_t ws_size,
                              hipStream_t stream) {
    const float* x      = (const float*)d_in[0];
    const int*   erow   = (const int*)d_in[1];
    const int*   ecol   = (const int*)d_in[2];
    const float* eval_  = (const float*)d_in[3];
    const float* W      = (const float*)d_in[4];
    const float* bias   = (const float*)d_in[5];
    const float* scale  = (const float*)d_in[6];
    const float* offset = (const float*)d_in[7];
    float* out = (float*)d_out;

    const int nE = in_sizes[1];
    const int nN = in_sizes[0] / D;

    size_t off = 0;
    auto take = [&](size_t bytes) {
        size_t o = off;
        off = (off + bytes + 255) & ~(size_t)255;
        return o;
    };
    const size_t o_counts = take((size_t)(nN + 1) * 4);
    const size_t o_rowptr = take((size_t)(nN + 1) * 4);
    const size_t o_sums   = take(1024 * 4);
    const size_t o_fill   = take((size_t)nN * 4);
    const size_t o_esort  = take((size_t)nE * 8);
    const bool use_csr = (ws_size >= off);

    if (use_csr) {
        char* ws = (char*)d_ws;
        int*  counts = (int*)(ws + o_counts);
        int*  rowptr = (int*)(ws + o_rowptr);
        int*  sums   = (int*)(ws + o_sums);
        int*  fill   = (int*)(ws + o_fill);
        int2* esort  = (int2*)(ws + o_esort);

        hipMemsetAsync(counts, 0, (size_t)(nN + 1) * 4, stream);
        hipMemsetAsync(fill,   0, (size_t)nN * 4, stream);

        hist_kernel<<<(nE + 255) / 256, 256, 0, stream>>>(erow, counts, nE);

        const int nScan = nN + 1;
        const int nb = (nScan + 1023) / 1024;
        scan1_kernel<<<nb, 1024, 0, stream>>>(counts, rowptr, sums, nScan);
        scan2_kernel<<<1, 1024, 0, stream>>>(sums, nb);
        scan3_kernel<<<nb, 1024, 0, stream>>>(rowptr, sums, nScan);

        scatter_kernel<<<(nE + 255) / 256, 256, 0, stream>>>(
            erow, ecol, eval_, rowptr, fill, esort, nE);

        spmm_pull_kernel<<<(nN + 3) / 4, 256, 0, stream>>>(
            x, rowptr, esort, out, nN);
    } else {
        hipMemsetAsync(out, 0, (size_t)nN * D * sizeof(float), stream);
        spmm_atomic_kernel<<<2048, 256, 0, stream>>>(x, erow, ecol, eval_, out, nE);
    }

    gemm_elu_norm_v2<<<768, 256, 0, stream>>>(out, W, bias, scale, offset, nN);
}

// Round 4
// 471.471 us; speedup vs baseline: 1.6744x; 1.6744x over previous
//
#include <hip/hip_runtime.h>
#include <cstddef>

#define D 128
#define EPSV 1e-9f
#define NB 8

__device__ __forceinline__ float wred64(float v) {
    #pragma unroll
    for (int off = 32; off > 0; off >>= 1) v += __shfl_xor(v, off, 64);
    return v;
}

// ===========================================================================
// CSR build: histogram -> 3-stage exclusive scan -> scatter (col,val) by row
// ===========================================================================
__global__ __launch_bounds__(256) void hist_kernel(
    const int* __restrict__ erow, int* __restrict__ counts, int nE)
{
    int i = blockIdx.x * 256 + threadIdx.x;
    if (i < nE) atomicAdd(&counts[erow[i]], 1);
}

__global__ __launch_bounds__(1024) void scan1_kernel(
    const int* __restrict__ in, int* __restrict__ out,
    int* __restrict__ sums, int n)
{
    __shared__ int tmp[1024];
    const int t = threadIdx.x;
    const int gid = blockIdx.x * 1024 + t;
    const int v = (gid < n) ? in[gid] : 0;
    tmp[t] = v;
    __syncthreads();
    #pragma unroll
    for (int d = 1; d < 1024; d <<= 1) {
        int u = (t >= d) ? tmp[t - d] : 0;
        __syncthreads();
        tmp[t] += u;
        __syncthreads();
    }
    if (gid < n) out[gid] = tmp[t] - v;
    if (t == 1023) sums[blockIdx.x] = tmp[t];
}

__global__ __launch_bounds__(1024) void scan2_kernel(int* __restrict__ sums, int nb)
{
    __shared__ int tmp[1024];
    const int t = threadIdx.x;
    const int v = (t < nb) ? sums[t] : 0;
    tmp[t] = v;
    __syncthreads();
    #pragma unroll
    for (int d = 1; d < 1024; d <<= 1) {
        int u = (t >= d) ? tmp[t - d] : 0;
        __syncthreads();
        tmp[t] += u;
        __syncthreads();
    }
    if (t < nb) sums[t] = tmp[t] - v;
}

__global__ __launch_bounds__(1024) void scan3_kernel(
    int* __restrict__ out, const int* __restrict__ sums, int n)
{
    int gid = blockIdx.x * 1024 + threadIdx.x;
    if (gid < n) out[gid] += sums[blockIdx.x];
}

__global__ __launch_bounds__(256) void scatter_kernel(
    const int* __restrict__ erow, const int* __restrict__ ecol,
    const float* __restrict__ eval_, const int* __restrict__ rowptr,
    int* __restrict__ fill, int2* __restrict__ esort, int nE)
{
    int i = blockIdx.x * 256 + threadIdx.x;
    if (i < nE) {
        const int r = erow[i];
        const int pos = rowptr[r] + atomicAdd(&fill[r], 1);
        esort[pos] = make_int2(ecol[i], __float_as_int(eval_[i]));
    }
}

// ===========================================================================
// Pull SpMM: one wave per node; unroll-4 edge walk, 2 accumulator chains.
// EPI=true applies bias+ELU+rownorm in the epilogue (src must then be
// y = x @ W^T); EPI=false writes raw aggregation.
// ===========================================================================
template <bool EPI>
__global__ __launch_bounds__(256) void spmm_pull(
    const float* __restrict__ src, const int* __restrict__ rowptr,
    const int2* __restrict__ es, float* __restrict__ dst,
    const float* __restrict__ bias, const float* __restrict__ scale,
    const float* __restrict__ offset, int nN)
{
    const int lane = threadIdx.x & 63;
    const int node = __builtin_amdgcn_readfirstlane(
        (int)((blockIdx.x * 256 + threadIdx.x) >> 6));
    if (node >= nN) return;
    const int s = rowptr[node];
    const int e = rowptr[node + 1];
    float2 acc = make_float2(0.f, 0.f);
    float2 acc2 = make_float2(0.f, 0.f);
    int j = s;
    for (; j + 3 < e; j += 4) {
        const int2 e0 = es[j];
        const int2 e1 = es[j + 1];
        const int2 e2 = es[j + 2];
        const int2 e3 = es[j + 3];
        const float2 x0 = ((const float2*)(src + (size_t)e0.x * D))[lane];
        const float2 x1 = ((const float2*)(src + (size_t)e1.x * D))[lane];
        const float2 x2 = ((const float2*)(src + (size_t)e2.x * D))[lane];
        const float2 x3 = ((const float2*)(src + (size_t)e3.x * D))[lane];
        const float v0 = __int_as_float(e0.y), v1 = __int_as_float(e1.y);
        const float v2 = __int_as_float(e2.y), v3 = __int_as_float(e3.y);
        acc.x  = fmaf(v0, x0.x, acc.x);  acc.y  = fmaf(v0, x0.y, acc.y);
        acc2.x = fmaf(v1, x1.x, acc2.x); acc2.y = fmaf(v1, x1.y, acc2.y);
        acc.x  = fmaf(v2, x2.x, acc.x);  acc.y  = fmaf(v2, x2.y, acc.y);
        acc2.x = fmaf(v3, x3.x, acc2.x); acc2.y = fmaf(v3, x3.y, acc2.y);
    }
    for (; j < e; ++j) {
        const int2 e0 = es[j];
        const float v0 = __int_as_float(e0.y);
        const float2 x0 = ((const float2*)(src + (size_t)e0.x * D))[lane];
        acc.x = fmaf(v0, x0.x, acc.x);
        acc.y = fmaf(v0, x0.y, acc.y);
    }
    acc.x += acc2.x; acc.y += acc2.y;

    if constexpr (EPI) {
        const float2 bv = ((const float2*)bias)[lane];
        float e0 = acc.x + bv.x, e1 = acc.y + bv.y;
        e0 = e0 > 0.f ? e0 : expm1f(e0);
        e1 = e1 > 0.f ? e1 : expm1f(e1);
        const float s_  = wred64(e0 + e1);
        const float sq  = wred64(e0 * e0 + e1 * e1);
        const float mean = s_ * (1.0f / D);
        const float var  = sq * (1.0f / D) - mean * mean;
        const float rs   = rsqrtf(var + EPSV);
        const float2 sv = ((const float2*)scale)[lane];
        const float2 ov = ((const float2*)offset)[lane];
        ((float2*)(dst + (size_t)node * D))[lane] =
            make_float2((e0 - mean) * sv.x * rs + ov.x,
                        (e1 - mean) * sv.y * rs + ov.y);
    } else {
        ((float2*)(dst + (size_t)node * D))[lane] = acc;
    }
}

// ===========================================================================
// Fallback (ws too small): push-style SpMM with HW f32 atomics
// ===========================================================================
__global__ __launch_bounds__(256) void spmm_atomic_kernel(
    const float* __restrict__ x, const int* __restrict__ erow,
    const int* __restrict__ ecol, const float* __restrict__ eval_,
    float* __restrict__ feat, int nEdges)
{
    const int lane = threadIdx.x & 63;
    int w = (int)((blockIdx.x * blockDim.x + threadIdx.x) >> 6);
    const int nW = (int)((gridDim.x * blockDim.x) >> 6);
    for (int e = w; e < nEdges; e += nW) {
        const int r = erow[e];
        const int c = ecol[e];
        const float v = eval_[e];
        const float2 xv = ((const float2*)(x + (size_t)c * D))[lane];
        float* fr = feat + (size_t)r * D + 2 * lane;
        unsafeAtomicAdd(fr,     v * xv.x);
        unsafeAtomicAdd(fr + 1, v * xv.y);
    }
}

// ===========================================================================
// GEMM core v3: W row held in 32 NAMED float4 VGPRs (no array -> no scratch).
// in rows staged in LDS (4KB/tile), consumed via uniform ds_read_b128
// (broadcast). Pure-FMA inner loop, 4 acc chains.
// EPI=true: +bias, ELU, per-row mean/var norm (in-place capable).
// EPI=false: raw  out = in @ W^T  (for the reordered pipeline).
// ===========================================================================
#define LW(i) const float4 w##i = Wp[i];
#define LW_ALL  LW(0) LW(1) LW(2) LW(3) LW(4) LW(5) LW(6) LW(7) \
                LW(8) LW(9) LW(10) LW(11) LW(12) LW(13) LW(14) LW(15) \
                LW(16) LW(17) LW(18) LW(19) LW(20) LW(21) LW(22) LW(23) \
                LW(24) LW(25) LW(26) LW(27) LW(28) LW(29) LW(30) LW(31)
#define GST(i) { const float4 f = Lf[i]; \
    a0 = fmaf(f.x, w##i.x, a0); a1 = fmaf(f.y, w##i.y, a1); \
    a2 = fmaf(f.z, w##i.z, a2); a3 = fmaf(f.w, w##i.w, a3); }
#define GST_ALL GST(0) GST(1) GST(2) GST(3) GST(4) GST(5) GST(6) GST(7) \
                GST(8) GST(9) GST(10) GST(11) GST(12) GST(13) GST(14) GST(15) \
                GST(16) GST(17) GST(18) GST(19) GST(20) GST(21) GST(22) GST(23) \
                GST(24) GST(25) GST(26) GST(27) GST(28) GST(29) GST(30) GST(31)

template <bool EPI>
__global__ __launch_bounds__(256, 2) void gemm_core(
    const float* in, float* outp,
    const float* __restrict__ W, const float* __restrict__ bias,
    const float* __restrict__ scale, const float* __restrict__ offset,
    int nNodes)
{
    __shared__ float  lfeat[NB][D];
    __shared__ float2 red[2][4][2];

    const int tid  = threadIdx.x;
    const int wave = tid >> 6;
    const int lane = tid & 63;
    const int p = wave >> 1;            // pair 0/1 -> nodes p*4 .. p*4+3
    const int h = wave & 1;             // output half
    const int o = h * 64 + lane;        // this lane's output column

    const float4* Wp = (const float4*)(W + (size_t)o * D);
    LW_ALL
    float bo = 0.f, sco = 0.f, ofo = 0.f;
    if constexpr (EPI) { bo = bias[o]; sco = scale[o]; ofo = offset[o]; }

    const int r_st = tid >> 5;          // staging row 0..7
    const int q    = tid & 31;          // float4 index within row

    for (int nbase = blockIdx.x * NB; nbase < nNodes; nbase += gridDim.x * NB) {
        {
            const int node = nbase + r_st;
            float4 v = make_float4(0.f, 0.f, 0.f, 0.f);
            if (node < nNodes) v = *(const float4*)&in[(size_t)node * D + q * 4];
            *(float4*)&lfeat[r_st][q * 4] = v;
        }
        __syncthreads();

        if constexpr (EPI) {
            float e[4];
            #pragma unroll
            for (int nd = 0; nd < 4; ++nd) {
                const float4* Lf = (const float4*)lfeat[p * 4 + nd];
                float a0 = 0.f, a1 = 0.f, a2 = 0.f, a3 = 0.f;
                GST_ALL
                float v = (a0 + a1) + (a2 + a3) + bo;
                v = v > 0.f ? v : expm1f(v);
                e[nd] = v;
                const float s  = wred64(v);
                const float sq = wred64(v * v);
                if (lane == 0) red[p][nd][h] = make_float2(s, sq);
            }
            __syncthreads();
            #pragma unroll
            for (int nd = 0; nd < 4; ++nd) {
                const int node = nbase + p * 4 + nd;
                if (node < nNodes) {
                    const float2 r0 = red[p][nd][0];
                    const float2 r1 = red[p][nd][1];
                    const float s  = r0.x + r1.x;
                    const float sq = r0.y + r1.y;
                    const float mean = s * (1.0f / D);
                    const float var  = sq * (1.0f / D) - mean * mean;
                    const float rs   = rsqrtf(var + EPSV);
                    outp[(size_t)node * D + o] = (e[nd] - mean) * sco * rs + ofo;
                }
            }
            __syncthreads();
        } else {
            #pragma unroll
            for (int nd = 0; nd < 4; ++nd) {
                const float4* Lf = (const float4*)lfeat[p * 4 + nd];
                float a0 = 0.f, a1 = 0.f, a2 = 0.f, a3 = 0.f;
                GST_ALL
                const int node = nbase + p * 4 + nd;
                if (node < nNodes)
                    outp[(size_t)node * D + o] = (a0 + a1) + (a2 + a3);
            }
            __syncthreads();
        }
    }
}

extern "C" void kernel_launch(void* const* d_in, const int* in_sizes, int n_in,
                              void* d_out, int out_size, void* d_ws, size_t ws_size,
                              hipStream_t stream) {
    const float* x      = (const float*)d_in[0];
    const int*   erow   = (const int*)d_in[1];
    const int*   ecol   = (const int*)d_in[2];
    const float* eval_  = (const float*)d_in[3];
    const float* W      = (const float*)d_in[4];
    const float* bias   = (const float*)d_in[5];
    const float* scale  = (const float*)d_in[6];
    const float* offset = (const float*)d_in[7];
    float* out = (float*)d_out;

    const int nE = in_sizes[1];
    const int nN = in_sizes[0] / D;

    size_t off = 0;
    auto take = [&](size_t bytes) {
        size_t o = off;
        off = (off + bytes + 255) & ~(size_t)255;
        return o;
    };
    const size_t o_counts = take((size_t)(nN + 1) * 4);
    const size_t o_rowptr = take((size_t)(nN + 1) * 4);
    const size_t o_sums   = take(1024 * 4);
    const size_t o_fill   = take((size_t)nN * 4);
    const size_t o_esort  = take((size_t)nE * 8);
    const size_t csr_need = off;
    const size_t o_y      = take((size_t)nN * D * 4);
    const size_t fused_need = off;

    const bool use_csr = (ws_size >= csr_need);
    const bool fused   = (ws_size >= fused_need);

    const int gemm_grid = (nN + NB - 1) / NB;

    if (use_csr) {
        char* ws = (char*)d_ws;
        int*  counts = (int*)(ws + o_counts);
        int*  rowptr = (int*)(ws + o_rowptr);
        int*  sums   = (int*)(ws + o_sums);
        int*  fill   = (int*)(ws + o_fill);
        int2* esort  = (int2*)(ws + o_esort);
        float* y     = (float*)(ws + o_y);

        hipMemsetAsync(counts, 0, (size_t)(nN + 1) * 4, stream);
        hipMemsetAsync(fill,   0, (size_t)nN * 4, stream);

        hist_kernel<<<(nE + 255) / 256, 256, 0, stream>>>(erow, counts, nE);

        const int nScan = nN + 1;
        const int nb = (nScan + 1023) / 1024;
        scan1_kernel<<<nb, 1024, 0, stream>>>(counts, rowptr, sums, nScan);
        scan2_kernel<<<1, 1024, 0, stream>>>(sums, nb);
        scan3_kernel<<<nb, 1024, 0, stream>>>(rowptr, sums, nScan);

        scatter_kernel<<<(nE + 255) / 256, 256, 0, stream>>>(
            erow, ecol, eval_, rowptr, fill, esort, nE);

        if (fused) {
            // y = x @ W^T, then aggregate y with fused bias/ELU/norm epilogue
            gemm_core<false><<<gemm_grid, 256, 0, stream>>>(
                x, y, W, nullptr, nullptr, nullptr, nN);
            spmm_pull<true><<<(nN + 3) / 4, 256, 0, stream>>>(
                y, rowptr, esort, out, bias, scale, offset, nN);
        } else {
            spmm_pull<false><<<(nN + 3) / 4, 256, 0, stream>>>(
                x, rowptr, esort, out, nullptr, nullptr, nullptr, nN);
            gemm_core<true><<<gemm_grid, 256, 0, stream>>>(
                out, out, W, bias, scale, offset, nN);
        }
    } else {
        hipMemsetAsync(out, 0, (size_t)nN * D * sizeof(float), stream);
        spmm_atomic_kernel<<<2048, 256, 0, stream>>>(x, erow, ecol, eval_, out, nE);
        gemm_core<true><<<gemm_grid, 256, 0, stream>>>(
            out, out, W, bias, scale, offset, nN);
    }
}

// Round 5
// 268.470 us; speedup vs baseline: 2.9404x; 1.7561x over previous
//
#include <hip/hip_runtime.h>
#include <cstddef>

#define D 128
#define EPSV 1e-9f
#define NB 8
#define LDA 136   // padded bf16 row stride (16B-aligned rows, conflict-free frags)

typedef __attribute__((ext_vector_type(8))) short bf16x8;
typedef __attribute__((ext_vector_type(4))) float f32x4;

__device__ __forceinline__ float wred64(float v) {
    #pragma unroll
    for (int off = 32; off > 0; off >>= 1) v += __shfl_xor(v, off, 64);
    return v;
}

__device__ __forceinline__ ushort f2bf(float f) {   // RNE f32 -> bf16 bits
    uint u = __float_as_uint(f);
    return (ushort)((u + 0x7fffu + ((u >> 16) & 1u)) >> 16);
}

// ===========================================================================
// CSR build: histogram -> 3-stage exclusive scan -> scatter (col,val) by row
// ===========================================================================
__global__ __launch_bounds__(256) void hist_kernel(
    const int* __restrict__ erow, int* __restrict__ counts, int nE)
{
    int i = blockIdx.x * 256 + threadIdx.x;
    if (i < nE) atomicAdd(&counts[erow[i]], 1);
}

__global__ __launch_bounds__(1024) void scan1_kernel(
    const int* __restrict__ in, int* __restrict__ out,
    int* __restrict__ sums, int n)
{
    __shared__ int tmp[1024];
    const int t = threadIdx.x;
    const int gid = blockIdx.x * 1024 + t;
    const int v = (gid < n) ? in[gid] : 0;
    tmp[t] = v;
    __syncthreads();
    #pragma unroll
    for (int d = 1; d < 1024; d <<= 1) {
        int u = (t >= d) ? tmp[t - d] : 0;
        __syncthreads();
        tmp[t] += u;
        __syncthreads();
    }
    if (gid < n) out[gid] = tmp[t] - v;
    if (t == 1023) sums[blockIdx.x] = tmp[t];
}

__global__ __launch_bounds__(1024) void scan2_kernel(int* __restrict__ sums, int nb)
{
    __shared__ int tmp[1024];
    const int t = threadIdx.x;
    const int v = (t < nb) ? sums[t] : 0;
    tmp[t] = v;
    __syncthreads();
    #pragma unroll
    for (int d = 1; d < 1024; d <<= 1) {
        int u = (t >= d) ? tmp[t - d] : 0;
        __syncthreads();
        tmp[t] += u;
        __syncthreads();
    }
    if (t < nb) sums[t] = tmp[t] - v;
}

__global__ __launch_bounds__(1024) void scan3_kernel(
    int* __restrict__ out, const int* __restrict__ sums, int n)
{
    int gid = blockIdx.x * 1024 + threadIdx.x;
    if (gid < n) out[gid] += sums[blockIdx.x];
}

__global__ __launch_bounds__(256) void scatter_kernel(
    const int* __restrict__ erow, const int* __restrict__ ecol,
    const float* __restrict__ eval_, const int* __restrict__ rowptr,
    int* __restrict__ fill, int2* __restrict__ esort, int nE)
{
    int i = blockIdx.x * 256 + threadIdx.x;
    if (i < nE) {
        const int r = erow[i];
        const int pos = rowptr[r] + atomicAdd(&fill[r], 1);
        esort[pos] = make_int2(ecol[i], __float_as_int(eval_[i]));
    }
}

// ===========================================================================
// W f32 [128][128] -> padded bf16 [128][136] in ws
// ===========================================================================
__global__ __launch_bounds__(256) void wconv_kernel(
    const float* __restrict__ W, ushort* __restrict__ Wb)
{
    int i = blockIdx.x * 256 + threadIdx.x;
    if (i < D * D) {
        const int n = i >> 7, k = i & 127;
        Wb[n * LDA + k] = f2bf(W[i]);
    }
}

// ===========================================================================
// MFMA GEMM: y(bf16) = x(f32->bf16) @ W^T.  Block = 64 rows x 128 cols.
// LDS: x-tile [64][136] bf16 (17KB) + W [128][136] bf16 (34KB) -> 3 blk/CU.
// Wave w: rows 16w..16w+15, all 8 col-tiles. Frags: 8 contiguous k per lane
// (A: row=l&15, k=(l>>4)*8+e; B: col=l&15, same k; D: col=l&15,
// row=(l>>4)*4+reg) -- per verified m92/m97 ladder layout.
// ===========================================================================
__global__ __launch_bounds__(256, 3) void xw_mfma(
    const float* __restrict__ x, const ushort* __restrict__ Wb,
    ushort* __restrict__ y, int nN)
{
    __shared__ ushort lx[64 * LDA];
    __shared__ ushort lw[128 * LDA];

    const int tid = threadIdx.x;
    const int nbase = blockIdx.x * 64;

    // stage W (linear 8B copies; pad bytes copied but never used in frags)
    for (int i = tid; i < (D * LDA) / 4; i += 256)
        ((ushort4*)lw)[i] = ((const ushort4*)Wb)[i];

    // stage x tile with f32->bf16 convert
    for (int i = tid; i < 64 * 32; i += 256) {
        const int r = i >> 5, c4 = i & 31;
        float4 v = make_float4(0.f, 0.f, 0.f, 0.f);
        if (nbase + r < nN) v = *(const float4*)&x[(size_t)(nbase + r) * D + c4 * 4];
        ushort4 h;
        h.x = f2bf(v.x); h.y = f2bf(v.y); h.z = f2bf(v.z); h.w = f2bf(v.w);
        *(ushort4*)&lx[r * LDA + c4 * 4] = h;
    }
    __syncthreads();

    const int w = tid >> 6, l = tid & 63;
    const int m = l & 15, g = l >> 4;
    const int rbase = w * 16;

    f32x4 acc[8] = {};
    #pragma unroll
    for (int kk = 0; kk < 4; ++kk) {
        const int k0 = kk * 32 + g * 8;
        const bf16x8 a = *(const bf16x8*)&lx[(rbase + m) * LDA + k0];
        #pragma unroll
        for (int t = 0; t < 8; ++t) {
            const bf16x8 b = *(const bf16x8*)&lw[(t * 16 + m) * LDA + k0];
            acc[t] = __builtin_amdgcn_mfma_f32_16x16x32_bf16(a, b, acc[t], 0, 0, 0);
        }
    }

    #pragma unroll
    for (int t = 0; t < 8; ++t) {
        #pragma unroll
        for (int r = 0; r < 4; ++r) {
            const int row = nbase + rbase + g * 4 + r;
            if (row < nN)
                y[(size_t)row * D + t * 16 + m] = f2bf(acc[t][r]);
        }
    }
}

// ===========================================================================
// Pull SpMM over bf16 y, fused bias+ELU+rownorm epilogue. One wave per node.
// Lane handles feats (2*lane, 2*lane+1) = one uint gather per edge (256B/row).
// ===========================================================================
__global__ __launch_bounds__(256) void spmm_pull_bf16(
    const ushort* __restrict__ y, const int* __restrict__ rowptr,
    const int2* __restrict__ es, float* __restrict__ dst,
    const float* __restrict__ bias, const float* __restrict__ scale,
    const float* __restrict__ offset, int nN)
{
    const int lane = threadIdx.x & 63;
    const int node = __builtin_amdgcn_readfirstlane(
        (int)((blockIdx.x * 256 + threadIdx.x) >> 6));
    if (node >= nN) return;
    const int s = rowptr[node];
    const int e = rowptr[node + 1];

    float a0 = 0.f, a1 = 0.f, b0 = 0.f, b1 = 0.f;
    int j = s;
    for (; j + 3 < e; j += 4) {
        const int2 e0 = es[j];
        const int2 e1 = es[j + 1];
        const int2 e2 = es[j + 2];
        const int2 e3 = es[j + 3];
        const uint u0 = ((const uint*)(y + (size_t)e0.x * D))[lane];
        const uint u1 = ((const uint*)(y + (size_t)e1.x * D))[lane];
        const uint u2 = ((const uint*)(y + (size_t)e2.x * D))[lane];
        const uint u3 = ((const uint*)(y + (size_t)e3.x * D))[lane];
        const float v0 = __int_as_float(e0.y), v1 = __int_as_float(e1.y);
        const float v2 = __int_as_float(e2.y), v3 = __int_as_float(e3.y);
        a0 = fmaf(v0, __uint_as_float(u0 << 16), a0);
        a1 = fmaf(v0, __uint_as_float(u0 & 0xffff0000u), a1);
        b0 = fmaf(v1, __uint_as_float(u1 << 16), b0);
        b1 = fmaf(v1, __uint_as_float(u1 & 0xffff0000u), b1);
        a0 = fmaf(v2, __uint_as_float(u2 << 16), a0);
        a1 = fmaf(v2, __uint_as_float(u2 & 0xffff0000u), a1);
        b0 = fmaf(v3, __uint_as_float(u3 << 16), b0);
        b1 = fmaf(v3, __uint_as_float(u3 & 0xffff0000u), b1);
    }
    for (; j < e; ++j) {
        const int2 e0 = es[j];
        const float v0 = __int_as_float(e0.y);
        const uint u0 = ((const uint*)(y + (size_t)e0.x * D))[lane];
        a0 = fmaf(v0, __uint_as_float(u0 << 16), a0);
        a1 = fmaf(v0, __uint_as_float(u0 & 0xffff0000u), a1);
    }

    const float2 bv = ((const float2*)bias)[lane];
    float e0 = a0 + b0 + bv.x, e1 = a1 + b1 + bv.y;
    e0 = e0 > 0.f ? e0 : expm1f(e0);
    e1 = e1 > 0.f ? e1 : expm1f(e1);
    const float s_  = wred64(e0 + e1);
    const float sq  = wred64(e0 * e0 + e1 * e1);
    const float mean = s_ * (1.0f / D);
    const float var  = sq * (1.0f / D) - mean * mean;
    const float rs   = rsqrtf(var + EPSV);
    const float2 sv = ((const float2*)scale)[lane];
    const float2 ov = ((const float2*)offset)[lane];
    ((float2*)(dst + (size_t)node * D))[lane] =
        make_float2((e0 - mean) * sv.x * rs + ov.x,
                    (e1 - mean) * sv.y * rs + ov.y);
}

// ===========================================================================
// f32 fallbacks (small-ws paths) -- kept from round 4
// ===========================================================================
template <bool EPI>
__global__ __launch_bounds__(256) void spmm_pull(
    const float* __restrict__ src, const int* __restrict__ rowptr,
    const int2* __restrict__ es, float* __restrict__ dst,
    const float* __restrict__ bias, const float* __restrict__ scale,
    const float* __restrict__ offset, int nN)
{
    const int lane = threadIdx.x & 63;
    const int node = __builtin_amdgcn_readfirstlane(
        (int)((blockIdx.x * 256 + threadIdx.x) >> 6));
    if (node >= nN) return;
    const int s = rowptr[node];
    const int e = rowptr[node + 1];
    float2 acc = make_float2(0.f, 0.f);
    float2 acc2 = make_float2(0.f, 0.f);
    int j = s;
    for (; j + 3 < e; j += 4) {
        const int2 e0 = es[j];
        const int2 e1 = es[j + 1];
        const int2 e2 = es[j + 2];
        const int2 e3 = es[j + 3];
        const float2 x0 = ((const float2*)(src + (size_t)e0.x * D))[lane];
        const float2 x1 = ((const float2*)(src + (size_t)e1.x * D))[lane];
        const float2 x2 = ((const float2*)(src + (size_t)e2.x * D))[lane];
        const float2 x3 = ((const float2*)(src + (size_t)e3.x * D))[lane];
        const float v0 = __int_as_float(e0.y), v1 = __int_as_float(e1.y);
        const float v2 = __int_as_float(e2.y), v3 = __int_as_float(e3.y);
        acc.x  = fmaf(v0, x0.x, acc.x);  acc.y  = fmaf(v0, x0.y, acc.y);
        acc2.x = fmaf(v1, x1.x, acc2.x); acc2.y = fmaf(v1, x1.y, acc2.y);
        acc.x  = fmaf(v2, x2.x, acc.x);  acc.y  = fmaf(v2, x2.y, acc.y);
        acc2.x = fmaf(v3, x3.x, acc2.x); acc2.y = fmaf(v3, x3.y, acc2.y);
    }
    for (; j < e; ++j) {
        const int2 e0 = es[j];
        const float v0 = __int_as_float(e0.y);
        const float2 x0 = ((const float2*)(src + (size_t)e0.x * D))[lane];
        acc.x = fmaf(v0, x0.x, acc.x);
        acc.y = fmaf(v0, x0.y, acc.y);
    }
    acc.x += acc2.x; acc.y += acc2.y;

    if constexpr (EPI) {
        const float2 bv = ((const float2*)bias)[lane];
        float e0 = acc.x + bv.x, e1 = acc.y + bv.y;
        e0 = e0 > 0.f ? e0 : expm1f(e0);
        e1 = e1 > 0.f ? e1 : expm1f(e1);
        const float s_  = wred64(e0 + e1);
        const float sq  = wred64(e0 * e0 + e1 * e1);
        const float mean = s_ * (1.0f / D);
        const float var  = sq * (1.0f / D) - mean * mean;
        const float rs   = rsqrtf(var + EPSV);
        const float2 sv = ((const float2*)scale)[lane];
        const float2 ov = ((const float2*)offset)[lane];
        ((float2*)(dst + (size_t)node * D))[lane] =
            make_float2((e0 - mean) * sv.x * rs + ov.x,
                        (e1 - mean) * sv.y * rs + ov.y);
    } else {
        ((float2*)(dst + (size_t)node * D))[lane] = acc;
    }
}

__global__ __launch_bounds__(256) void spmm_atomic_kernel(
    const float* __restrict__ x, const int* __restrict__ erow,
    const int* __restrict__ ecol, const float* __restrict__ eval_,
    float* __restrict__ feat, int nEdges)
{
    const int lane = threadIdx.x & 63;
    int w = (int)((blockIdx.x * blockDim.x + threadIdx.x) >> 6);
    const int nW = (int)((gridDim.x * blockDim.x) >> 6);
    for (int e = w; e < nEdges; e += nW) {
        const int r = erow[e];
        const int c = ecol[e];
        const float v = eval_[e];
        const float2 xv = ((const float2*)(x + (size_t)c * D))[lane];
        float* fr = feat + (size_t)r * D + 2 * lane;
        unsafeAtomicAdd(fr,     v * xv.x);
        unsafeAtomicAdd(fr + 1, v * xv.y);
    }
}

#define LW(i) const float4 w##i = Wp[i];
#define LW_ALL  LW(0) LW(1) LW(2) LW(3) LW(4) LW(5) LW(6) LW(7) \
                LW(8) LW(9) LW(10) LW(11) LW(12) LW(13) LW(14) LW(15) \
                LW(16) LW(17) LW(18) LW(19) LW(20) LW(21) LW(22) LW(23) \
                LW(24) LW(25) LW(26) LW(27) LW(28) LW(29) LW(30) LW(31)
#define GST(i) { const float4 f = Lf[i]; \
    a0 = fmaf(f.x, w##i.x, a0); a1 = fmaf(f.y, w##i.y, a1); \
    a2 = fmaf(f.z, w##i.z, a2); a3 = fmaf(f.w, w##i.w, a3); }
#define GST_ALL GST(0) GST(1) GST(2) GST(3) GST(4) GST(5) GST(6) GST(7) \
                GST(8) GST(9) GST(10) GST(11) GST(12) GST(13) GST(14) GST(15) \
                GST(16) GST(17) GST(18) GST(19) GST(20) GST(21) GST(22) GST(23) \
                GST(24) GST(25) GST(26) GST(27) GST(28) GST(29) GST(30) GST(31)

__global__ __launch_bounds__(256, 2) void gemm_epi_f32(
    const float* in, float* outp,
    const float* __restrict__ W, const float* __restrict__ bias,
    const float* __restrict__ scale, const float* __restrict__ offset,
    int nNodes)
{
    __shared__ float  lfeat[NB][D];
    __shared__ float2 red[2][4][2];

    const int tid  = threadIdx.x;
    const int wave = tid >> 6;
    const int lane = tid & 63;
    const int p = wave >> 1;
    const int h = wave & 1;
    const int o = h * 64 + lane;

    const float4* Wp = (const float4*)(W + (size_t)o * D);
    LW_ALL
    const float bo = bias[o], sco = scale[o], ofo = offset[o];

    const int r_st = tid >> 5;
    const int q    = tid & 31;

    for (int nbase = blockIdx.x * NB; nbase < nNodes; nbase += gridDim.x * NB) {
        {
            const int node = nbase + r_st;
            float4 v = make_float4(0.f, 0.f, 0.f, 0.f);
            if (node < nNodes) v = *(const float4*)&in[(size_t)node * D + q * 4];
            *(float4*)&lfeat[r_st][q * 4] = v;
        }
        __syncthreads();
        float e[4];
        #pragma unroll
        for (int nd = 0; nd < 4; ++nd) {
            const float4* Lf = (const float4*)lfeat[p * 4 + nd];
            float a0 = 0.f, a1 = 0.f, a2 = 0.f, a3 = 0.f;
            GST_ALL
            float v = (a0 + a1) + (a2 + a3) + bo;
            v = v > 0.f ? v : expm1f(v);
            e[nd] = v;
            const float s  = wred64(v);
            const float sq = wred64(v * v);
            if (lane == 0) red[p][nd][h] = make_float2(s, sq);
        }
        __syncthreads();
        #pragma unroll
        for (int nd = 0; nd < 4; ++nd) {
            const int node = nbase + p * 4 + nd;
            if (node < nNodes) {
                const float2 r0 = red[p][nd][0];
                const float2 r1 = red[p][nd][1];
                const float s  = r0.x + r1.x;
                const float sq = r0.y + r1.y;
                const float mean = s * (1.0f / D);
                const float var  = sq * (1.0f / D) - mean * mean;
                const float rs   = rsqrtf(var + EPSV);
                outp[(size_t)node * D + o] = (e[nd] - mean) * sco * rs + ofo;
            }
        }
        __syncthreads();
    }
}

extern "C" void kernel_launch(void* const* d_in, const int* in_sizes, int n_in,
                              void* d_out, int out_size, void* d_ws, size_t ws_size,
                              hipStream_t stream) {
    const float* x      = (const float*)d_in[0];
    const int*   erow   = (const int*)d_in[1];
    const int*   ecol   = (const int*)d_in[2];
    const float* eval_  = (const float*)d_in[3];
    const float* W      = (const float*)d_in[4];
    const float* bias   = (const float*)d_in[5];
    const float* scale  = (const float*)d_in[6];
    const float* offset = (const float*)d_in[7];
    float* out = (float*)d_out;

    const int nE = in_sizes[1];
    const int nN = in_sizes[0] / D;

    size_t off = 0;
    auto take = [&](size_t bytes) {
        size_t o = off;
        off = (off + bytes + 255) & ~(size_t)255;
        return o;
    };
    const size_t o_counts = take((size_t)(nN + 1) * 4);
    const size_t o_rowptr = take((size_t)(nN + 1) * 4);
    const size_t o_sums   = take(1024 * 4);
    const size_t o_fill   = take((size_t)nN * 4);
    const size_t o_esort  = take((size_t)nE * 8);
    const size_t csr_need = off;
    const size_t o_wb     = take((size_t)D * LDA * 2);
    const size_t o_y      = take((size_t)nN * D * 2);
    const size_t fused_need = off;

    const bool use_csr = (ws_size >= csr_need);
    const bool fused   = (ws_size >= fused_need);

    if (use_csr) {
        char* ws = (char*)d_ws;
        int*  counts = (int*)(ws + o_counts);
        int*  rowptr = (int*)(ws + o_rowptr);
        int*  sums   = (int*)(ws + o_sums);
        int*  fill   = (int*)(ws + o_fill);
        int2* esort  = (int2*)(ws + o_esort);

        hipMemsetAsync(counts, 0, (size_t)(nN + 1) * 4, stream);
        hipMemsetAsync(fill,   0, (size_t)nN * 4, stream);

        hist_kernel<<<(nE + 255) / 256, 256, 0, stream>>>(erow, counts, nE);

        const int nScan = nN + 1;
        const int nb = (nScan + 1023) / 1024;
        scan1_kernel<<<nb, 1024, 0, stream>>>(counts, rowptr, sums, nScan);
        scan2_kernel<<<1, 1024, 0, stream>>>(sums, nb);
        scan3_kernel<<<nb, 1024, 0, stream>>>(rowptr, sums, nScan);

        scatter_kernel<<<(nE + 255) / 256, 256, 0, stream>>>(
            erow, ecol, eval_, rowptr, fill, esort, nE);

        if (fused) {
            ushort* wb = (ushort*)(ws + o_wb);
            ushort* y  = (ushort*)(ws + o_y);
            wconv_kernel<<<(D * D + 255) / 256, 256, 0, stream>>>(W, wb);
            xw_mfma<<<(nN + 63) / 64, 256, 0, stream>>>(x, wb, y, nN);
            spmm_pull_bf16<<<(nN + 3) / 4, 256, 0, stream>>>(
                y, rowptr, esort, out, bias, scale, offset, nN);
        } else {
            spmm_pull<false><<<(nN + 3) / 4, 256, 0, stream>>>(
                x, rowptr, esort, out, nullptr, nullptr, nullptr, nN);
            gemm_epi_f32<<<(nN + NB - 1) / NB, 256, 0, stream>>>(
                out, out, W, bias, scale, offset, nN);
        }
    } else {
        hipMemsetAsync(out, 0, (size_t)nN * D * sizeof(float), stream);
        spmm_atomic_kernel<<<2048, 256, 0, stream>>>(x, erow, ecol, eval_, out, nE);
        gemm_epi_f32<<<(nN + NB - 1) / NB, 256, 0, stream>>>(
            out, out, W, bias, scale, offset, nN);
    }
}